// Round 1
// baseline (737.855 us; speedup 1.0000x reference)
//
#include <hip/hip_runtime.h>

// Problem constants (fixed by reference)
#define NB  16     // batch
#define CC  256    // channels
#define SH  64     // H
#define SW  64     // W
#define HWP 4096   // H*W
#define NSLICE (NB * CC)          // 4096 attention slices (b, c=n*32+d)
#define OUT_ELEMS ((size_t)NB * CC * HWP)   // 16,777,216

// ---------------------------------------------------------------------------
// Projection GEMM: Y[b][o][p] = sum_c W[o][c] * X[b][c][p] + bias[o]
// Block: 256 threads computes a 64(o) x 64(p) tile for one batch b.
// Grid: (NB*64, 4). LDS: sX[k][p] natural, sW[k][o] transposed.
// ---------------------------------------------------------------------------
__global__ __launch_bounds__(256) void proj_kernel(
    const float* __restrict__ X, const float* __restrict__ W,
    const float* __restrict__ bias, float* __restrict__ Y)
{
    __shared__ float sX[64][68];   // sX[kk][pp]
    __shared__ float sW[64][68];   // sW[kk][oo]  (W transposed)

    const int tid = threadIdx.x;
    const int tr  = tid & 15;      // p-direction (4 floats each)
    const int tc  = tid >> 4;      // o-direction (4 floats each)
    const int b   = blockIdx.x >> 6;
    const int p0  = (blockIdx.x & 63) << 6;
    const int o0  = blockIdx.y << 6;

    const float* Xb = X + (size_t)b * CC * HWP;

    float acc[4][4] = {};

    for (int c0 = 0; c0 < CC; c0 += 64) {
        __syncthreads();   // protect LDS from previous iteration's readers
        // ---- load X chunk: sX[kk][pp] = X[b][c0+kk][p0+pp]
        #pragma unroll
        for (int it = 0; it < 4; ++it) {
            const int kk = tc + it * 16;
            const int p4 = tr << 2;
            const float4 xv = *(const float4*)&Xb[(c0 + kk) * HWP + p0 + p4];
            *(float4*)&sX[kk][p4] = xv;
        }
        // ---- load W chunk transposed: sW[kk][oo] = W[o0+oo][c0+kk]
        {
            const int oo0 = tc << 2;
            const int kk0 = tr << 2;
            const float* src = W + (size_t)(o0 + oo0) * CC + c0 + kk0;
            const float4 w0 = *(const float4*)(src);
            const float4 w1 = *(const float4*)(src + CC);
            const float4 w2 = *(const float4*)(src + 2 * CC);
            const float4 w3 = *(const float4*)(src + 3 * CC);
            *(float4*)&sW[kk0 + 0][oo0] = make_float4(w0.x, w1.x, w2.x, w3.x);
            *(float4*)&sW[kk0 + 1][oo0] = make_float4(w0.y, w1.y, w2.y, w3.y);
            *(float4*)&sW[kk0 + 2][oo0] = make_float4(w0.z, w1.z, w2.z, w3.z);
            *(float4*)&sW[kk0 + 3][oo0] = make_float4(w0.w, w1.w, w2.w, w3.w);
        }
        __syncthreads();
        // ---- compute
        #pragma unroll
        for (int k = 0; k < 64; ++k) {
            const float4 av = *(const float4*)&sW[k][tc << 2];
            const float4 xv = *(const float4*)&sX[k][tr << 2];
            const float a[4] = {av.x, av.y, av.z, av.w};
            const float x[4] = {xv.x, xv.y, xv.z, xv.w};
            #pragma unroll
            for (int i = 0; i < 4; ++i)
                #pragma unroll
                for (int j = 0; j < 4; ++j)
                    acc[i][j] = fmaf(a[i], x[j], acc[i][j]);
        }
    }

    // ---- epilogue: bias + store
    #pragma unroll
    for (int i = 0; i < 4; ++i) {
        const int o = o0 + (tc << 2) + i;
        const float bv = bias[o];
        float4 r;
        r.x = acc[i][0] + bv;
        r.y = acc[i][1] + bv;
        r.z = acc[i][2] + bv;
        r.w = acc[i][3] + bv;
        *(float4*)&Y[((size_t)b * CC + o) * HWP + p0 + (tr << 2)] = r;
    }
}

// ---------------------------------------------------------------------------
// Attention: one block per slice s = b*256 + (n*32+d). 64x64 Q,K,V over w.
//   logits[h][g] = (1/8) * sum_w Q[h][w] K[g][w];  P = softmax_g(logits)
//   out[h][w]    = sum_g P[h][g] V[g][w]
// NOTE: attn_out may alias kh, out_pre may alias qh (slice-local, ordered by
// __syncthreads between the LDS load phase and all global writes). Therefore
// NO __restrict__ on pointer params here.
// ---------------------------------------------------------------------------
__global__ __launch_bounds__(256) void attn_kernel(
    const float* qh, const float* kh, const float* vh,
    float* attn_out, float* out_pre)
{
    __shared__ float Qt[64][68];   // Qt[w][h]; reused as Pt[g][h] after QK^T
    __shared__ float Kt[64][68];   // Kt[w][g]
    __shared__ float Vs[64][68];   // Vs[g][w]

    const int tid  = threadIdx.x;
    const int tr   = tid & 15;
    const int tc   = tid >> 4;
    const int s    = blockIdx.x;
    const size_t base = (size_t)s * HWP;

    // ---- load Q transposed: Qt[w][h]
    {
        const int r0 = tc << 2;        // h block
        const int c0 = tr << 2;        // w block
        const float* src = qh + base + r0 * SW + c0;
        const float4 a0 = *(const float4*)(src);
        const float4 a1 = *(const float4*)(src + SW);
        const float4 a2 = *(const float4*)(src + 2 * SW);
        const float4 a3 = *(const float4*)(src + 3 * SW);
        *(float4*)&Qt[c0 + 0][r0] = make_float4(a0.x, a1.x, a2.x, a3.x);
        *(float4*)&Qt[c0 + 1][r0] = make_float4(a0.y, a1.y, a2.y, a3.y);
        *(float4*)&Qt[c0 + 2][r0] = make_float4(a0.z, a1.z, a2.z, a3.z);
        *(float4*)&Qt[c0 + 3][r0] = make_float4(a0.w, a1.w, a2.w, a3.w);
    }
    // ---- load K transposed: Kt[w][g]
    {
        const int r0 = tc << 2;        // g block
        const int c0 = tr << 2;        // w block
        const float* src = kh + base + r0 * SW + c0;
        const float4 a0 = *(const float4*)(src);
        const float4 a1 = *(const float4*)(src + SW);
        const float4 a2 = *(const float4*)(src + 2 * SW);
        const float4 a3 = *(const float4*)(src + 3 * SW);
        *(float4*)&Kt[c0 + 0][r0] = make_float4(a0.x, a1.x, a2.x, a3.x);
        *(float4*)&Kt[c0 + 1][r0] = make_float4(a0.y, a1.y, a2.y, a3.y);
        *(float4*)&Kt[c0 + 2][r0] = make_float4(a0.z, a1.z, a2.z, a3.z);
        *(float4*)&Kt[c0 + 3][r0] = make_float4(a0.w, a1.w, a2.w, a3.w);
    }
    // ---- load V natural: Vs[g][w]
    #pragma unroll
    for (int it = 0; it < 4; ++it) {
        const int g = tc + it * 16;
        const float4 vv = *(const float4*)&vh[base + g * SW + (tr << 2)];
        *(float4*)&Vs[g][tr << 2] = vv;
    }
    __syncthreads();

    // ---- QK^T: thread owns rows h=tc*4..+4, cols g=tr*4..+4
    float acc[4][4] = {};
    #pragma unroll
    for (int w = 0; w < 64; ++w) {
        const float4 av = *(const float4*)&Qt[w][tc << 2];
        const float4 bv = *(const float4*)&Kt[w][tr << 2];
        const float a[4] = {av.x, av.y, av.z, av.w};
        const float g[4] = {bv.x, bv.y, bv.z, bv.w};
        #pragma unroll
        for (int i = 0; i < 4; ++i)
            #pragma unroll
            for (int j = 0; j < 4; ++j)
                acc[i][j] = fmaf(a[i], g[j], acc[i][j]);
    }

    // ---- softmax over g (row h spread over 16 lanes: same tc, tr=0..15)
    float p[4][4];
    #pragma unroll
    for (int i = 0; i < 4; ++i) {
        float l0 = acc[i][0] * 0.125f;
        float l1 = acc[i][1] * 0.125f;
        float l2 = acc[i][2] * 0.125f;
        float l3 = acc[i][3] * 0.125f;
        float m = fmaxf(fmaxf(l0, l1), fmaxf(l2, l3));
        m = fmaxf(m, __shfl_xor(m, 1));
        m = fmaxf(m, __shfl_xor(m, 2));
        m = fmaxf(m, __shfl_xor(m, 4));
        m = fmaxf(m, __shfl_xor(m, 8));
        const float e0 = __expf(l0 - m);
        const float e1 = __expf(l1 - m);
        const float e2 = __expf(l2 - m);
        const float e3 = __expf(l3 - m);
        float sum = e0 + e1 + e2 + e3;
        sum += __shfl_xor(sum, 1);
        sum += __shfl_xor(sum, 2);
        sum += __shfl_xor(sum, 4);
        sum += __shfl_xor(sum, 8);
        const float rs = 1.0f / sum;
        p[i][0] = e0 * rs;
        p[i][1] = e1 * rs;
        p[i][2] = e2 * rs;
        p[i][3] = e3 * rs;
    }

    // ---- write attn to global: attn[s][h][g]
    #pragma unroll
    for (int i = 0; i < 4; ++i) {
        float4 r = make_float4(p[i][0], p[i][1], p[i][2], p[i][3]);
        *(float4*)&attn_out[base + (size_t)((tc << 2) + i) * SH + (tr << 2)] = r;
    }

    __syncthreads();   // all reads of Qt done -> safe to overwrite with Pt

    // ---- store P transposed into Qt buffer: Pt[g][h]
    #pragma unroll
    for (int j = 0; j < 4; ++j) {
        *(float4*)&Qt[(tr << 2) + j][tc << 2] =
            make_float4(p[0][j], p[1][j], p[2][j], p[3][j]);
    }
    __syncthreads();

    // ---- PV: out[h][w] = sum_g P[h][g] V[g][w]
    float o[4][4] = {};
    #pragma unroll
    for (int g = 0; g < 64; ++g) {
        const float4 av = *(const float4*)&Qt[g][tc << 2];   // Pt[g][h..]
        const float4 bv = *(const float4*)&Vs[g][tr << 2];
        const float a[4] = {av.x, av.y, av.z, av.w};
        const float v[4] = {bv.x, bv.y, bv.z, bv.w};
        #pragma unroll
        for (int i = 0; i < 4; ++i)
            #pragma unroll
            for (int j = 0; j < 4; ++j)
                o[i][j] = fmaf(a[i], v[j], o[i][j]);
    }
    #pragma unroll
    for (int i = 0; i < 4; ++i) {
        float4 r = make_float4(o[i][0], o[i][1], o[i][2], o[i][3]);
        *(float4*)&out_pre[base + (size_t)((tc << 2) + i) * SW + (tr << 2)] = r;
    }
}

// ---------------------------------------------------------------------------
// Memory plan (minimizes ws usage to 64 MiB):
//   vh      -> d_out[0 : 16.78M)       (fully consumed by attn before final
//                                       proj overwrites this region)
//   kh      -> d_out[16.78M : 33.55M)  (attn half; block s reads slice s to
//                                       LDS before writing attn slice s)
//   qh      -> ws[0 : 16.78M)
//   out_pre -> aliases qh              (slice-local, barrier-ordered)
// ---------------------------------------------------------------------------
extern "C" void kernel_launch(void* const* d_in, const int* in_sizes, int n_in,
                              void* d_out, int out_size, void* d_ws, size_t ws_size,
                              hipStream_t stream) {
    (void)in_sizes; (void)n_in; (void)out_size; (void)ws_size;

    const float* q  = (const float*)d_in[0];
    const float* k  = (const float*)d_in[1];
    const float* v  = (const float*)d_in[2];
    const float* Wq = (const float*)d_in[3];
    const float* bq = (const float*)d_in[4];
    const float* Wk = (const float*)d_in[5];
    const float* bk = (const float*)d_in[6];
    const float* Wv = (const float*)d_in[7];
    const float* bv = (const float*)d_in[8];
    const float* Wo = (const float*)d_in[9];
    const float* bo = (const float*)d_in[10];

    float* out  = (float*)d_out;
    float* attn = out + OUT_ELEMS;

    float* vh      = out;             // reused, consumed before overwrite
    float* kh      = attn;            // reused, slice-local overwrite
    float* qh      = (float*)d_ws;
    float* out_pre = qh;              // alias, slice-local

    const dim3 gproj(NB * 64, 4);
    const dim3 blk(256);

    proj_kernel<<<gproj, blk, 0, stream>>>(q, Wq, bq, qh);
    proj_kernel<<<gproj, blk, 0, stream>>>(k, Wk, bk, kh);
    proj_kernel<<<gproj, blk, 0, stream>>>(v, Wv, bv, vh);

    attn_kernel<<<dim3(NSLICE), blk, 0, stream>>>(qh, kh, vh, attn, out_pre);

    proj_kernel<<<gproj, blk, 0, stream>>>(out_pre, Wo, bo, out);
}

// Round 2
// 463.294 us; speedup vs baseline: 1.5926x; 1.5926x over previous
//
#include <hip/hip_runtime.h>

// Problem constants (fixed by reference)
#define NB  16     // batch
#define CC  256    // channels
#define SH  64     // H
#define SW  64     // W
#define HWP 4096   // H*W
#define NSLICE (NB * CC)          // 4096 attention slices
#define OUT_ELEMS ((size_t)NB * CC * HWP)   // 16,777,216
#define PADK 40    // 32 + 8 pad (bf16 elems) -> 80 B rows, 2-way max read conflict

using bf16x8 = __attribute__((ext_vector_type(8))) short;   // 8 bf16 = 4 VGPRs
using f32x4  = __attribute__((ext_vector_type(4))) float;

// pack top-16-bits (truncation toward zero) of two fp32 into one u32 (x0 low)
__device__ __forceinline__ unsigned pack_hi16(unsigned u0, unsigned u1) {
    return __builtin_amdgcn_perm(u1, u0, 0x07060302u);
}
__device__ __forceinline__ float trunc_bf(unsigned u) {
    union { unsigned u; float f; } v; v.u = u & 0xFFFF0000u; return v.f;
}
__device__ __forceinline__ unsigned fbits(float x) {
    union { float f; unsigned u; } v; v.f = x; return v.u;
}

// ---------------------------------------------------------------------------
// Split-bf16 MFMA projection: Y[b][o][p] = sum_c W[o][c] X[b][c][p] + bias[o]
// Y ~= Whi*Xhi + Whi*Xlo + Wlo*Xhi  (lo*lo dropped, ~2^-28 relative)
// Block: 128(o) x 128(p), 4 waves 2x2, BK=32. Grid (2, 32, 16).
// ---------------------------------------------------------------------------
__global__ __launch_bounds__(256) void proj_mfma_kernel(
    const float* __restrict__ X, const float* __restrict__ W,
    const float* __restrict__ bias, float* __restrict__ Y)
{
    __shared__ short sWhi[128][PADK];   // [o][k]
    __shared__ short sWlo[128][PADK];
    __shared__ short sXhi[128][PADK];   // [p][k]  (X transposed)
    __shared__ short sXlo[128][PADK];

    const int tid = threadIdx.x;
    const int o0  = blockIdx.x * 128;
    const int p0  = blockIdx.y * 128;
    const int b   = blockIdx.z;
    const float* Xb = X + (size_t)b * CC * HWP;

    const int wid  = tid >> 6;
    const int lane = tid & 63;
    const int wr = wid >> 1, wc = wid & 1;     // wave 2x2 over (o, p)
    const int l16 = lane & 15, lq = lane >> 4;

    // staging decomposition
    const int kq = tid & 7;          // W: k-quad (4 bf16)
    const int ooB = tid >> 3;        // W: o row base (0..31), +32 per pass
    const int cb = tid & 7;          // X: c-block of 4
    const int pb = tid >> 3;         // X: p-block of 4 (0..31)

    f32x4 acc[4][4] = {};

    for (int c0 = 0; c0 < CC; c0 += 32) {
        __syncthreads();   // previous iteration's LDS readers done

        // ---- stage W tile 128x32 (each thread: 4 rows x 4 k)
        #pragma unroll
        for (int pass = 0; pass < 4; ++pass) {
            const int oo = ooB + pass * 32;
            const float4 wv = *(const float4*)&W[(size_t)(o0 + oo) * CC + c0 + kq * 4];
            const unsigned u0 = fbits(wv.x), u1 = fbits(wv.y),
                           u2 = fbits(wv.z), u3 = fbits(wv.w);
            const float r0 = wv.x - trunc_bf(u0);
            const float r1 = wv.y - trunc_bf(u1);
            const float r2 = wv.z - trunc_bf(u2);
            const float r3 = wv.w - trunc_bf(u3);
            uint2 hi, lo;
            hi.x = pack_hi16(u0, u1);          hi.y = pack_hi16(u2, u3);
            lo.x = pack_hi16(fbits(r0), fbits(r1));
            lo.y = pack_hi16(fbits(r2), fbits(r3));
            *(uint2*)&sWhi[oo][kq * 4] = hi;
            *(uint2*)&sWlo[oo][kq * 4] = lo;
        }

        // ---- stage X tile 32x128, transposed to [p][k] (each thread: 4x4 block)
        {
            const float* xsrc = Xb + (size_t)(c0 + cb * 4) * HWP + p0 + pb * 4;
            const float4 x0 = *(const float4*)(xsrc);
            const float4 x1 = *(const float4*)(xsrc + HWP);
            const float4 x2 = *(const float4*)(xsrc + 2 * HWP);
            const float4 x3 = *(const float4*)(xsrc + 3 * HWP);
            const float c0v[4][4] = {{x0.x, x1.x, x2.x, x3.x},
                                     {x0.y, x1.y, x2.y, x3.y},
                                     {x0.z, x1.z, x2.z, x3.z},
                                     {x0.w, x1.w, x2.w, x3.w}};
            #pragma unroll
            for (int j = 0; j < 4; ++j) {
                const unsigned u0 = fbits(c0v[j][0]), u1 = fbits(c0v[j][1]),
                               u2 = fbits(c0v[j][2]), u3 = fbits(c0v[j][3]);
                const float r0 = c0v[j][0] - trunc_bf(u0);
                const float r1 = c0v[j][1] - trunc_bf(u1);
                const float r2 = c0v[j][2] - trunc_bf(u2);
                const float r3 = c0v[j][3] - trunc_bf(u3);
                uint2 hi, lo;
                hi.x = pack_hi16(u0, u1);          hi.y = pack_hi16(u2, u3);
                lo.x = pack_hi16(fbits(r0), fbits(r1));
                lo.y = pack_hi16(fbits(r2), fbits(r3));
                *(uint2*)&sXhi[pb * 4 + j][cb * 4] = hi;
                *(uint2*)&sXlo[pb * 4 + j][cb * 4] = lo;
            }
        }
        __syncthreads();

        // ---- MFMA: 16 fragments x 3 products
        const int aRow = wr * 64 + l16;
        const int bRow = wc * 64 + l16;
        bf16x8 bhi[4], blo[4];
        #pragma unroll
        for (int fn = 0; fn < 4; ++fn) {
            bhi[fn] = *(const bf16x8*)&sXhi[bRow + fn * 16][lq * 8];
            blo[fn] = *(const bf16x8*)&sXlo[bRow + fn * 16][lq * 8];
        }
        #pragma unroll
        for (int fm = 0; fm < 4; ++fm) {
            const bf16x8 ahi = *(const bf16x8*)&sWhi[aRow + fm * 16][lq * 8];
            const bf16x8 alo = *(const bf16x8*)&sWlo[aRow + fm * 16][lq * 8];
            #pragma unroll
            for (int fn = 0; fn < 4; ++fn) {
                acc[fm][fn] = __builtin_amdgcn_mfma_f32_16x16x32_bf16(
                    ahi, bhi[fn], acc[fm][fn], 0, 0, 0);
                acc[fm][fn] = __builtin_amdgcn_mfma_f32_16x16x32_bf16(
                    ahi, blo[fn], acc[fm][fn], 0, 0, 0);
                acc[fm][fn] = __builtin_amdgcn_mfma_f32_16x16x32_bf16(
                    alo, bhi[fn], acc[fm][fn], 0, 0, 0);
            }
        }
    }

    // ---- epilogue: bias + store (C/D: col = lane&15, row = (lane>>4)*4 + reg)
    #pragma unroll
    for (int fm = 0; fm < 4; ++fm) {
        #pragma unroll
        for (int j = 0; j < 4; ++j) {
            const int o = o0 + wr * 64 + fm * 16 + lq * 4 + j;
            const float bv = bias[o];
            #pragma unroll
            for (int fn = 0; fn < 4; ++fn) {
                Y[((size_t)b * CC + o) * HWP + p0 + wc * 64 + fn * 16 + l16] =
                    acc[fm][fn][j] + bv;
            }
        }
    }
}

// ---------------------------------------------------------------------------
// Attention: one block per slice s. (unchanged from round 1 — known-good)
// attn_out may alias kh, out_pre may alias qh (slice-local, barrier-ordered),
// so NO __restrict__ here.
// ---------------------------------------------------------------------------
__global__ __launch_bounds__(256) void attn_kernel(
    const float* qh, const float* kh, const float* vh,
    float* attn_out, float* out_pre)
{
    __shared__ float Qt[64][68];   // Qt[w][h]; reused as Pt[g][h]
    __shared__ float Kt[64][68];   // Kt[w][g]
    __shared__ float Vs[64][68];   // Vs[g][w]

    const int tid  = threadIdx.x;
    const int tr   = tid & 15;
    const int tc   = tid >> 4;
    const int s    = blockIdx.x;
    const size_t base = (size_t)s * HWP;

    {
        const int r0 = tc << 2, c0 = tr << 2;
        const float* src = qh + base + r0 * SW + c0;
        const float4 a0 = *(const float4*)(src);
        const float4 a1 = *(const float4*)(src + SW);
        const float4 a2 = *(const float4*)(src + 2 * SW);
        const float4 a3 = *(const float4*)(src + 3 * SW);
        *(float4*)&Qt[c0 + 0][r0] = make_float4(a0.x, a1.x, a2.x, a3.x);
        *(float4*)&Qt[c0 + 1][r0] = make_float4(a0.y, a1.y, a2.y, a3.y);
        *(float4*)&Qt[c0 + 2][r0] = make_float4(a0.z, a1.z, a2.z, a3.z);
        *(float4*)&Qt[c0 + 3][r0] = make_float4(a0.w, a1.w, a2.w, a3.w);
    }
    {
        const int r0 = tc << 2, c0 = tr << 2;
        const float* src = kh + base + r0 * SW + c0;
        const float4 a0 = *(const float4*)(src);
        const float4 a1 = *(const float4*)(src + SW);
        const float4 a2 = *(const float4*)(src + 2 * SW);
        const float4 a3 = *(const float4*)(src + 3 * SW);
        *(float4*)&Kt[c0 + 0][r0] = make_float4(a0.x, a1.x, a2.x, a3.x);
        *(float4*)&Kt[c0 + 1][r0] = make_float4(a0.y, a1.y, a2.y, a3.y);
        *(float4*)&Kt[c0 + 2][r0] = make_float4(a0.z, a1.z, a2.z, a3.z);
        *(float4*)&Kt[c0 + 3][r0] = make_float4(a0.w, a1.w, a2.w, a3.w);
    }
    #pragma unroll
    for (int it = 0; it < 4; ++it) {
        const int g = tc + it * 16;
        const float4 vv = *(const float4*)&vh[base + g * SW + (tr << 2)];
        *(float4*)&Vs[g][tr << 2] = vv;
    }
    __syncthreads();

    float accq[4][4] = {};
    #pragma unroll
    for (int w = 0; w < 64; ++w) {
        const float4 av = *(const float4*)&Qt[w][tc << 2];
        const float4 bv = *(const float4*)&Kt[w][tr << 2];
        const float a[4] = {av.x, av.y, av.z, av.w};
        const float g[4] = {bv.x, bv.y, bv.z, bv.w};
        #pragma unroll
        for (int i = 0; i < 4; ++i)
            #pragma unroll
            for (int j = 0; j < 4; ++j)
                accq[i][j] = fmaf(a[i], g[j], accq[i][j]);
    }

    float p[4][4];
    #pragma unroll
    for (int i = 0; i < 4; ++i) {
        float l0 = accq[i][0] * 0.125f;
        float l1 = accq[i][1] * 0.125f;
        float l2 = accq[i][2] * 0.125f;
        float l3 = accq[i][3] * 0.125f;
        float m = fmaxf(fmaxf(l0, l1), fmaxf(l2, l3));
        m = fmaxf(m, __shfl_xor(m, 1));
        m = fmaxf(m, __shfl_xor(m, 2));
        m = fmaxf(m, __shfl_xor(m, 4));
        m = fmaxf(m, __shfl_xor(m, 8));
        const float e0 = __expf(l0 - m);
        const float e1 = __expf(l1 - m);
        const float e2 = __expf(l2 - m);
        const float e3 = __expf(l3 - m);
        float sum = e0 + e1 + e2 + e3;
        sum += __shfl_xor(sum, 1);
        sum += __shfl_xor(sum, 2);
        sum += __shfl_xor(sum, 4);
        sum += __shfl_xor(sum, 8);
        const float rs = 1.0f / sum;
        p[i][0] = e0 * rs; p[i][1] = e1 * rs;
        p[i][2] = e2 * rs; p[i][3] = e3 * rs;
    }

    #pragma unroll
    for (int i = 0; i < 4; ++i) {
        float4 r = make_float4(p[i][0], p[i][1], p[i][2], p[i][3]);
        *(float4*)&attn_out[base + (size_t)((tc << 2) + i) * SH + (tr << 2)] = r;
    }

    __syncthreads();
    #pragma unroll
    for (int j = 0; j < 4; ++j) {
        *(float4*)&Qt[(tr << 2) + j][tc << 2] =
            make_float4(p[0][j], p[1][j], p[2][j], p[3][j]);
    }
    __syncthreads();

    float o[4][4] = {};
    #pragma unroll
    for (int g = 0; g < 64; ++g) {
        const float4 av = *(const float4*)&Qt[g][tc << 2];
        const float4 bv = *(const float4*)&Vs[g][tr << 2];
        const float a[4] = {av.x, av.y, av.z, av.w};
        const float v[4] = {bv.x, bv.y, bv.z, bv.w};
        #pragma unroll
        for (int i = 0; i < 4; ++i)
            #pragma unroll
            for (int j = 0; j < 4; ++j)
                o[i][j] = fmaf(a[i], v[j], o[i][j]);
    }
    #pragma unroll
    for (int i = 0; i < 4; ++i) {
        float4 r = make_float4(o[i][0], o[i][1], o[i][2], o[i][3]);
        *(float4*)&out_pre[base + (size_t)((tc << 2) + i) * SW + (tr << 2)] = r;
    }
}

// Memory plan (unchanged):
//   vh -> d_out[0:16.78M), kh -> d_out[16.78M:33.55M), qh -> ws, out_pre -> ws
extern "C" void kernel_launch(void* const* d_in, const int* in_sizes, int n_in,
                              void* d_out, int out_size, void* d_ws, size_t ws_size,
                              hipStream_t stream) {
    (void)in_sizes; (void)n_in; (void)out_size; (void)ws_size;

    const float* q  = (const float*)d_in[0];
    const float* k  = (const float*)d_in[1];
    const float* v  = (const float*)d_in[2];
    const float* Wq = (const float*)d_in[3];
    const float* bq = (const float*)d_in[4];
    const float* Wk = (const float*)d_in[5];
    const float* bk = (const float*)d_in[6];
    const float* Wv = (const float*)d_in[7];
    const float* bv = (const float*)d_in[8];
    const float* Wo = (const float*)d_in[9];
    const float* bo = (const float*)d_in[10];

    float* out  = (float*)d_out;
    float* attn = out + OUT_ELEMS;

    float* vh      = out;
    float* kh      = attn;
    float* qh      = (float*)d_ws;
    float* out_pre = qh;

    const dim3 gproj(2, 32, NB);   // (o-tiles fastest for X L2 reuse, p-tiles, b)
    const dim3 blk(256);

    proj_mfma_kernel<<<gproj, blk, 0, stream>>>(q, Wq, bq, qh);
    proj_mfma_kernel<<<gproj, blk, 0, stream>>>(k, Wk, bk, kh);
    proj_mfma_kernel<<<gproj, blk, 0, stream>>>(v, Wv, bv, vh);

    attn_kernel<<<dim3(NSLICE), blk, 0, stream>>>(qh, kh, vh, attn, out_pre);

    proj_mfma_kernel<<<gproj, blk, 0, stream>>>(out_pre, Wo, bo, out);
}

// Round 3
// 454.843 us; speedup vs baseline: 1.6222x; 1.0186x over previous
//
#include <hip/hip_runtime.h>

// Problem constants (fixed by reference)
#define NB  16     // batch
#define CC  256    // channels
#define SH  64     // H
#define SW  64     // W
#define HWP 4096   // H*W
#define NSLICE (NB * CC)          // 4096 attention slices
#define OUT_ELEMS ((size_t)NB * CC * HWP)   // 16,777,216
#define PADK 40    // 32 + 8 pad (bf16 elems)

using bf16x8 = __attribute__((ext_vector_type(8))) short;   // 8 bf16 = 4 VGPRs
using f32x4  = __attribute__((ext_vector_type(4))) float;

static __device__ __forceinline__ unsigned pack_hi16(unsigned u0, unsigned u1) {
    return __builtin_amdgcn_perm(u1, u0, 0x07060302u);   // (u1.hi16, u0.hi16)
}
static __device__ __forceinline__ float trunc_bf(unsigned u) {
    union { unsigned u; float f; } v; v.u = u & 0xFFFF0000u; return v.f;
}
static __device__ __forceinline__ unsigned fbits(float x) {
    union { float f; unsigned u; } v; v.f = x; return v.u;
}

// split 8 consecutive fp32 (two float4) into hi/lo bf16x8 fragments
static __device__ __forceinline__ void split8(float4 a, float4 b,
                                              bf16x8& hi, bf16x8& lo) {
    union { bf16x8 v; unsigned u[4]; } H, L;
    const float f[8] = {a.x, a.y, a.z, a.w, b.x, b.y, b.z, b.w};
    #pragma unroll
    for (int j = 0; j < 4; ++j) {
        const unsigned u0 = fbits(f[2 * j]), u1 = fbits(f[2 * j + 1]);
        const float r0 = f[2 * j]     - trunc_bf(u0);
        const float r1 = f[2 * j + 1] - trunc_bf(u1);
        H.u[j] = pack_hi16(u0, u1);
        L.u[j] = pack_hi16(fbits(r0), fbits(r1));
    }
    hi = H.v; lo = L.v;
}

// ---------------------------------------------------------------------------
// Split-bf16 MFMA projection body (verbatim logic from round 2 — verified).
// Y[b][o][p] = sum_c W[o][c] X[b][c][p] + bias[o]
// ---------------------------------------------------------------------------
static __device__ __forceinline__ void proj_body(
    const float* __restrict__ X, const float* __restrict__ W,
    const float* __restrict__ bias, float* __restrict__ Y,
    int b, int o0, int p0)
{
    __shared__ short sWhi[128][PADK];   // [o][k]
    __shared__ short sWlo[128][PADK];
    __shared__ short sXhi[128][PADK];   // [p][k]  (X transposed)
    __shared__ short sXlo[128][PADK];

    const int tid = threadIdx.x;
    const float* Xb = X + (size_t)b * CC * HWP;

    const int wid  = tid >> 6;
    const int lane = tid & 63;
    const int wr = wid >> 1, wc = wid & 1;     // wave 2x2 over (o, p)
    const int l16 = lane & 15, lq = lane >> 4;

    const int kq = tid & 7;          // W: k-quad (4 bf16)
    const int ooB = tid >> 3;        // W: o row base (0..31), +32 per pass
    const int cb = tid & 7;          // X: c-block of 4
    const int pb = tid >> 3;         // X: p-block of 4 (0..31)

    f32x4 acc[4][4] = {};

    for (int c0 = 0; c0 < CC; c0 += 32) {
        __syncthreads();
        #pragma unroll
        for (int pass = 0; pass < 4; ++pass) {
            const int oo = ooB + pass * 32;
            const float4 wv = *(const float4*)&W[(size_t)(o0 + oo) * CC + c0 + kq * 4];
            const unsigned u0 = fbits(wv.x), u1 = fbits(wv.y),
                           u2 = fbits(wv.z), u3 = fbits(wv.w);
            const float r0 = wv.x - trunc_bf(u0);
            const float r1 = wv.y - trunc_bf(u1);
            const float r2 = wv.z - trunc_bf(u2);
            const float r3 = wv.w - trunc_bf(u3);
            uint2 hi, lo;
            hi.x = pack_hi16(u0, u1);          hi.y = pack_hi16(u2, u3);
            lo.x = pack_hi16(fbits(r0), fbits(r1));
            lo.y = pack_hi16(fbits(r2), fbits(r3));
            *(uint2*)&sWhi[oo][kq * 4] = hi;
            *(uint2*)&sWlo[oo][kq * 4] = lo;
        }
        {
            const float* xsrc = Xb + (size_t)(c0 + cb * 4) * HWP + p0 + pb * 4;
            const float4 x0 = *(const float4*)(xsrc);
            const float4 x1 = *(const float4*)(xsrc + HWP);
            const float4 x2 = *(const float4*)(xsrc + 2 * HWP);
            const float4 x3 = *(const float4*)(xsrc + 3 * HWP);
            const float c0v[4][4] = {{x0.x, x1.x, x2.x, x3.x},
                                     {x0.y, x1.y, x2.y, x3.y},
                                     {x0.z, x1.z, x2.z, x3.z},
                                     {x0.w, x1.w, x2.w, x3.w}};
            #pragma unroll
            for (int j = 0; j < 4; ++j) {
                const unsigned u0 = fbits(c0v[j][0]), u1 = fbits(c0v[j][1]),
                               u2 = fbits(c0v[j][2]), u3 = fbits(c0v[j][3]);
                const float r0 = c0v[j][0] - trunc_bf(u0);
                const float r1 = c0v[j][1] - trunc_bf(u1);
                const float r2 = c0v[j][2] - trunc_bf(u2);
                const float r3 = c0v[j][3] - trunc_bf(u3);
                uint2 hi, lo;
                hi.x = pack_hi16(u0, u1);          hi.y = pack_hi16(u2, u3);
                lo.x = pack_hi16(fbits(r0), fbits(r1));
                lo.y = pack_hi16(fbits(r2), fbits(r3));
                *(uint2*)&sXhi[pb * 4 + j][cb * 4] = hi;
                *(uint2*)&sXlo[pb * 4 + j][cb * 4] = lo;
            }
        }
        __syncthreads();

        const int aRow = wr * 64 + l16;
        const int bRow = wc * 64 + l16;
        bf16x8 bhi[4], blo[4];
        #pragma unroll
        for (int fn = 0; fn < 4; ++fn) {
            bhi[fn] = *(const bf16x8*)&sXhi[bRow + fn * 16][lq * 8];
            blo[fn] = *(const bf16x8*)&sXlo[bRow + fn * 16][lq * 8];
        }
        #pragma unroll
        for (int fm = 0; fm < 4; ++fm) {
            const bf16x8 ahi = *(const bf16x8*)&sWhi[aRow + fm * 16][lq * 8];
            const bf16x8 alo = *(const bf16x8*)&sWlo[aRow + fm * 16][lq * 8];
            #pragma unroll
            for (int fn = 0; fn < 4; ++fn) {
                acc[fm][fn] = __builtin_amdgcn_mfma_f32_16x16x32_bf16(
                    ahi, bhi[fn], acc[fm][fn], 0, 0, 0);
                acc[fm][fn] = __builtin_amdgcn_mfma_f32_16x16x32_bf16(
                    ahi, blo[fn], acc[fm][fn], 0, 0, 0);
                acc[fm][fn] = __builtin_amdgcn_mfma_f32_16x16x32_bf16(
                    alo, bhi[fn], acc[fm][fn], 0, 0, 0);
            }
        }
    }

    #pragma unroll
    for (int fm = 0; fm < 4; ++fm) {
        #pragma unroll
        for (int j = 0; j < 4; ++j) {
            const int o = o0 + wr * 64 + fm * 16 + lq * 4 + j;
            const float bv = bias[o];
            #pragma unroll
            for (int fn = 0; fn < 4; ++fn) {
                Y[((size_t)b * CC + o) * HWP + p0 + wc * 64 + fn * 16 + l16] =
                    acc[fm][fn][j] + bv;
            }
        }
    }
}

// Fused q/k/v projections: grid (2, 32, 48); z = which*16 + b
__global__ __launch_bounds__(256) void proj_qkv_kernel(
    const float* __restrict__ q, const float* __restrict__ Wq,
    const float* __restrict__ bq, float* __restrict__ qh,
    const float* __restrict__ k, const float* __restrict__ Wk,
    const float* __restrict__ bk, float* __restrict__ kh,
    const float* __restrict__ v, const float* __restrict__ Wv,
    const float* __restrict__ bv, float* __restrict__ vh)
{
    const int which = blockIdx.z >> 4;
    const int b     = blockIdx.z & 15;
    const float* X  = (which == 0) ? q  : (which == 1) ? k  : v;
    const float* W  = (which == 0) ? Wq : (which == 1) ? Wk : Wv;
    const float* bi = (which == 0) ? bq : (which == 1) ? bk : bv;
    float*       Y  = (which == 0) ? qh : (which == 1) ? kh : vh;
    proj_body(X, W, bi, Y, b, blockIdx.x * 128, blockIdx.y * 128);
}

// Output projection: grid (2, 32, 16)
__global__ __launch_bounds__(256) void proj_o_kernel(
    const float* __restrict__ X, const float* __restrict__ W,
    const float* __restrict__ bias, float* __restrict__ Y)
{
    proj_body(X, W, bias, Y, blockIdx.z, blockIdx.x * 128, blockIdx.y * 128);
}

// ---------------------------------------------------------------------------
// MFMA attention: one WAVE per slice, 4 slices per block. Split-bf16 QK^T and
// PV; softmax in-register; P transposed via tiny per-wave [16][68] LDS buffer.
// Aliasing (attn_out~kh, out_pre~qh, all slice/wave-local, dep-ordered) ->
// NO __restrict__ on pointers.
// ---------------------------------------------------------------------------
__global__ __launch_bounds__(256) void attn_mfma_kernel(
    const float* qh, const float* kh, const float* vh,
    float* attn_out, float* out_pre)
{
    __shared__ float Pb[4][16][68];   // per-wave P^T bounce buffer (one m-tile)

    const int tid  = threadIdx.x;
    const int wid  = tid >> 6;
    const int lane = tid & 63;
    const int l16  = lane & 15;
    const int lq   = lane >> 4;

    const int s = blockIdx.x * 4 + wid;
    const size_t base = (size_t)s * HWP;
    const float* Q = qh + base;
    const float* K = kh + base;
    const float* V = vh + base;
    float (*P)[68] = Pb[wid];

    // ---- K fragments: B[k=w][n=g]; lane: K[g=nt*16+l16][w=ks*32+lq*8+0..7]
    bf16x8 Khi[4][2], Klo[4][2];
    #pragma unroll
    for (int nt = 0; nt < 4; ++nt)
        #pragma unroll
        for (int ks = 0; ks < 2; ++ks) {
            const float* src = K + (nt * 16 + l16) * SW + ks * 32 + lq * 8;
            split8(*(const float4*)src, *(const float4*)(src + 4),
                   Khi[nt][ks], Klo[nt][ks]);
        }

    // ---- QK^T: acc[mt][nt], C row = h = mt*16+lq*4+reg, col = g = nt*16+l16
    f32x4 acc[4][4] = {};
    #pragma unroll
    for (int mt = 0; mt < 4; ++mt) {
        bf16x8 Qhi[2], Qlo[2];
        #pragma unroll
        for (int ks = 0; ks < 2; ++ks) {
            const float* src = Q + (mt * 16 + l16) * SW + ks * 32 + lq * 8;
            split8(*(const float4*)src, *(const float4*)(src + 4),
                   Qhi[ks], Qlo[ks]);
        }
        #pragma unroll
        for (int nt = 0; nt < 4; ++nt)
            #pragma unroll
            for (int ks = 0; ks < 2; ++ks) {
                acc[mt][nt] = __builtin_amdgcn_mfma_f32_16x16x32_bf16(
                    Qhi[ks], Khi[nt][ks], acc[mt][nt], 0, 0, 0);
                acc[mt][nt] = __builtin_amdgcn_mfma_f32_16x16x32_bf16(
                    Qhi[ks], Klo[nt][ks], acc[mt][nt], 0, 0, 0);
                acc[mt][nt] = __builtin_amdgcn_mfma_f32_16x16x32_bf16(
                    Qlo[ks], Khi[nt][ks], acc[mt][nt], 0, 0, 0);
            }
    }

    // ---- V fragments (needed for all m-tiles): B[k=g][n=w]
    bf16x8 Vhi[4][2], Vlo[4][2];
    #pragma unroll
    for (int nt = 0; nt < 4; ++nt)
        #pragma unroll
        for (int ks = 0; ks < 2; ++ks) {
            const float* vcol = V + nt * 16 + l16;
            float f[8];
            #pragma unroll
            for (int e = 0; e < 8; ++e)
                f[e] = vcol[(ks * 32 + lq * 8 + e) * SW];
            split8(make_float4(f[0], f[1], f[2], f[3]),
                   make_float4(f[4], f[5], f[6], f[7]),
                   Vhi[nt][ks], Vlo[nt][ks]);
        }

    // ---- per m-tile: softmax -> global P + LDS transpose -> PV -> store out
    #pragma unroll
    for (int mt = 0; mt < 4; ++mt) {
        #pragma unroll
        for (int r = 0; r < 4; ++r) {
            float l0 = acc[mt][0][r] * 0.125f;
            float l1 = acc[mt][1][r] * 0.125f;
            float l2 = acc[mt][2][r] * 0.125f;
            float l3 = acc[mt][3][r] * 0.125f;
            float m = fmaxf(fmaxf(l0, l1), fmaxf(l2, l3));
            m = fmaxf(m, __shfl_xor(m, 1));
            m = fmaxf(m, __shfl_xor(m, 2));
            m = fmaxf(m, __shfl_xor(m, 4));
            m = fmaxf(m, __shfl_xor(m, 8));
            const float e0 = __expf(l0 - m);
            const float e1 = __expf(l1 - m);
            const float e2 = __expf(l2 - m);
            const float e3 = __expf(l3 - m);
            float sum = e0 + e1 + e2 + e3;
            sum += __shfl_xor(sum, 1);
            sum += __shfl_xor(sum, 2);
            sum += __shfl_xor(sum, 4);
            sum += __shfl_xor(sum, 8);
            const float rs = 1.0f / sum;
            const float p0 = e0 * rs, p1 = e1 * rs, p2 = e2 * rs, p3 = e3 * rs;
            const int h = mt * 16 + lq * 4 + r;
            float* gdst = attn_out + base + (size_t)h * SH;
            gdst[0 * 16 + l16] = p0;
            gdst[1 * 16 + l16] = p1;
            gdst[2 * 16 + l16] = p2;
            gdst[3 * 16 + l16] = p3;
            const int hr = lq * 4 + r;           // row within this m-tile
            P[hr][0 * 16 + l16] = p0;
            P[hr][1 * 16 + l16] = p1;
            P[hr][2 * 16 + l16] = p2;
            P[hr][3 * 16 + l16] = p3;
        }
        // A-frags of P for this m-tile: row = l16, k-run g = ks*32 + lq*8
        // (LDS ops are in-order per wave; buffer is wave-private)
        f32x4 o[4] = {};
        #pragma unroll
        for (int ks = 0; ks < 2; ++ks) {
            const float* src = &P[l16][ks * 32 + lq * 8];
            bf16x8 Phi, Plo;
            split8(*(const float4*)src, *(const float4*)(src + 4), Phi, Plo);
            #pragma unroll
            for (int nt = 0; nt < 4; ++nt) {
                o[nt] = __builtin_amdgcn_mfma_f32_16x16x32_bf16(
                    Phi, Vhi[nt][ks], o[nt], 0, 0, 0);
                o[nt] = __builtin_amdgcn_mfma_f32_16x16x32_bf16(
                    Phi, Vlo[nt][ks], o[nt], 0, 0, 0);
                o[nt] = __builtin_amdgcn_mfma_f32_16x16x32_bf16(
                    Plo, Vhi[nt][ks], o[nt], 0, 0, 0);
            }
        }
        #pragma unroll
        for (int nt = 0; nt < 4; ++nt)
            #pragma unroll
            for (int r = 0; r < 4; ++r)
                out_pre[base + (size_t)(mt * 16 + lq * 4 + r) * SW + nt * 16 + l16] =
                    o[nt][r];
    }
}

// Memory plan (unchanged):
//   vh -> d_out[0:16.78M), kh -> d_out[16.78M:33.55M), qh -> ws, out_pre -> ws
extern "C" void kernel_launch(void* const* d_in, const int* in_sizes, int n_in,
                              void* d_out, int out_size, void* d_ws, size_t ws_size,
                              hipStream_t stream) {
    (void)in_sizes; (void)n_in; (void)out_size; (void)ws_size;

    const float* q  = (const float*)d_in[0];
    const float* k  = (const float*)d_in[1];
    const float* v  = (const float*)d_in[2];
    const float* Wq = (const float*)d_in[3];
    const float* bq = (const float*)d_in[4];
    const float* Wk = (const float*)d_in[5];
    const float* bk = (const float*)d_in[6];
    const float* Wv = (const float*)d_in[7];
    const float* bv = (const float*)d_in[8];
    const float* Wo = (const float*)d_in[9];
    const float* bo = (const float*)d_in[10];

    float* out  = (float*)d_out;
    float* attn = out + OUT_ELEMS;

    float* vh      = out;
    float* kh      = attn;
    float* qh      = (float*)d_ws;
    float* out_pre = qh;

    const dim3 blk(256);

    proj_qkv_kernel<<<dim3(2, 32, 48), blk, 0, stream>>>(
        q, Wq, bq, qh, k, Wk, bk, kh, v, Wv, bv, vh);

    attn_mfma_kernel<<<dim3(NSLICE / 4), blk, 0, stream>>>(
        qh, kh, vh, attn, out_pre);

    proj_o_kernel<<<dim3(2, 32, 16), blk, 0, stream>>>(out_pre, Wo, bo, out);
}

// Round 6
// 419.775 us; speedup vs baseline: 1.7577x; 1.0835x over previous
//
#include <hip/hip_runtime.h>

// Problem constants (fixed by reference)
#define NB  16     // batch
#define CC  256    // channels
#define SH  64     // H
#define SW  64     // W
#define HWP 4096   // H*W
#define NSLICE (NB * CC)          // 4096 attention slices
#define OUT_ELEMS ((size_t)NB * CC * HWP)   // 16,777,216
#define PADK 40    // 32 + 8 pad (bf16 elems)

using bf16x8 = __attribute__((ext_vector_type(8))) short;   // 8 bf16 = 4 VGPRs
using f32x4  = __attribute__((ext_vector_type(4))) float;

static __device__ __forceinline__ unsigned pack_hi16(unsigned u0, unsigned u1) {
    return __builtin_amdgcn_perm(u1, u0, 0x07060302u);   // (u1.hi16, u0.hi16)
}
static __device__ __forceinline__ float trunc_bf(unsigned u) {
    union { unsigned u; float f; } v; v.u = u & 0xFFFF0000u; return v.f;
}
static __device__ __forceinline__ unsigned fbits(float x) {
    union { float f; unsigned u; } v; v.f = x; return v.u;
}

// split 8 consecutive fp32 (two float4) into hi/lo bf16x8 fragments
static __device__ __forceinline__ void split8(float4 a, float4 b,
                                              bf16x8& hi, bf16x8& lo) {
    union { bf16x8 v; unsigned u[4]; } H, L;
    const float f[8] = {a.x, a.y, a.z, a.w, b.x, b.y, b.z, b.w};
    #pragma unroll
    for (int j = 0; j < 4; ++j) {
        const unsigned u0 = fbits(f[2 * j]), u1 = fbits(f[2 * j + 1]);
        const float r0 = f[2 * j]     - trunc_bf(u0);
        const float r1 = f[2 * j + 1] - trunc_bf(u1);
        H.u[j] = pack_hi16(u0, u1);
        L.u[j] = pack_hi16(fbits(r0), fbits(r1));
    }
    hi = H.v; lo = L.v;
}

// ---------------------------------------------------------------------------
// Split-bf16 MFMA projection, software-pipelined (prefetch next K-step's
// global loads into registers before the MFMA phase — T14 issue-early).
// Y[b][o][p] = sum_c W[o][c] X[b][c][p] + bias[o]
// ---------------------------------------------------------------------------
static __device__ __forceinline__ void proj_body(
    const float* __restrict__ X, const float* __restrict__ W,
    const float* __restrict__ bias, float* __restrict__ Y,
    int b, int o0, int p0)
{
    __shared__ short sWhi[128][PADK];   // [o][k]
    __shared__ short sWlo[128][PADK];
    __shared__ short sXhi[128][PADK];   // [p][k]  (X transposed)
    __shared__ short sXlo[128][PADK];

    const int tid = threadIdx.x;
    const float* Xb = X + (size_t)b * CC * HWP;

    const int wid  = tid >> 6;
    const int lane = tid & 63;
    const int wr = wid >> 1, wc = wid & 1;     // wave 2x2 over (o, p)
    const int l16 = lane & 15, lq = lane >> 4;

    const int kq = tid & 7;          // W: k-quad (4 floats)
    const int ooB = tid >> 3;        // W: o row base (0..31), +32 per pass
    const int cb = tid & 7;          // X: c-block of 4
    const int pb = tid >> 3;         // X: p-block of 4 (0..31)

    f32x4 acc[4][4] = {};
    float4 wreg[4], xreg[4];

    // ---- prologue: issue loads for K-step 0
    #pragma unroll
    for (int pass = 0; pass < 4; ++pass)
        wreg[pass] = *(const float4*)&W[(size_t)(o0 + ooB + pass * 32) * CC + kq * 4];
    {
        const float* xsrc = Xb + (size_t)(cb * 4) * HWP + p0 + pb * 4;
        xreg[0] = *(const float4*)(xsrc);
        xreg[1] = *(const float4*)(xsrc + HWP);
        xreg[2] = *(const float4*)(xsrc + 2 * HWP);
        xreg[3] = *(const float4*)(xsrc + 3 * HWP);
    }

    for (int t = 0; t < 8; ++t) {
        __syncthreads();   // previous step's LDS readers done
        // ---- convert regs -> LDS (W)
        #pragma unroll
        for (int pass = 0; pass < 4; ++pass) {
            const int oo = ooB + pass * 32;
            const float4 wv = wreg[pass];
            const unsigned u0 = fbits(wv.x), u1 = fbits(wv.y),
                           u2 = fbits(wv.z), u3 = fbits(wv.w);
            const float r0 = wv.x - trunc_bf(u0);
            const float r1 = wv.y - trunc_bf(u1);
            const float r2 = wv.z - trunc_bf(u2);
            const float r3 = wv.w - trunc_bf(u3);
            uint2 hi, lo;
            hi.x = pack_hi16(u0, u1);          hi.y = pack_hi16(u2, u3);
            lo.x = pack_hi16(fbits(r0), fbits(r1));
            lo.y = pack_hi16(fbits(r2), fbits(r3));
            *(uint2*)&sWhi[oo][kq * 4] = hi;
            *(uint2*)&sWlo[oo][kq * 4] = lo;
        }
        // ---- convert regs -> LDS (X, transposed 4x4)
        {
            const float c0v[4][4] = {{xreg[0].x, xreg[1].x, xreg[2].x, xreg[3].x},
                                     {xreg[0].y, xreg[1].y, xreg[2].y, xreg[3].y},
                                     {xreg[0].z, xreg[1].z, xreg[2].z, xreg[3].z},
                                     {xreg[0].w, xreg[1].w, xreg[2].w, xreg[3].w}};
            #pragma unroll
            for (int j = 0; j < 4; ++j) {
                const unsigned u0 = fbits(c0v[j][0]), u1 = fbits(c0v[j][1]),
                               u2 = fbits(c0v[j][2]), u3 = fbits(c0v[j][3]);
                const float r0 = c0v[j][0] - trunc_bf(u0);
                const float r1 = c0v[j][1] - trunc_bf(u1);
                const float r2 = c0v[j][2] - trunc_bf(u2);
                const float r3 = c0v[j][3] - trunc_bf(u3);
                uint2 hi, lo;
                hi.x = pack_hi16(u0, u1);          hi.y = pack_hi16(u2, u3);
                lo.x = pack_hi16(fbits(r0), fbits(r1));
                lo.y = pack_hi16(fbits(r2), fbits(r3));
                *(uint2*)&sXhi[pb * 4 + j][cb * 4] = hi;
                *(uint2*)&sXlo[pb * 4 + j][cb * 4] = lo;
            }
        }
        __syncthreads();

        // ---- issue NEXT step's global loads (overlap with MFMA below)
        if (t < 7) {
            const int c0n = (t + 1) * 32;
            #pragma unroll
            for (int pass = 0; pass < 4; ++pass)
                wreg[pass] = *(const float4*)
                    &W[(size_t)(o0 + ooB + pass * 32) * CC + c0n + kq * 4];
            const float* xsrc = Xb + (size_t)(c0n + cb * 4) * HWP + p0 + pb * 4;
            xreg[0] = *(const float4*)(xsrc);
            xreg[1] = *(const float4*)(xsrc + HWP);
            xreg[2] = *(const float4*)(xsrc + 2 * HWP);
            xreg[3] = *(const float4*)(xsrc + 3 * HWP);
        }

        // ---- MFMA phase
        const int aRow = wr * 64 + l16;
        const int bRow = wc * 64 + l16;
        bf16x8 bhi[4], blo[4];
        #pragma unroll
        for (int fn = 0; fn < 4; ++fn) {
            bhi[fn] = *(const bf16x8*)&sXhi[bRow + fn * 16][lq * 8];
            blo[fn] = *(const bf16x8*)&sXlo[bRow + fn * 16][lq * 8];
        }
        #pragma unroll
        for (int fm = 0; fm < 4; ++fm) {
            const bf16x8 ahi = *(const bf16x8*)&sWhi[aRow + fm * 16][lq * 8];
            const bf16x8 alo = *(const bf16x8*)&sWlo[aRow + fm * 16][lq * 8];
            #pragma unroll
            for (int fn = 0; fn < 4; ++fn) {
                acc[fm][fn] = __builtin_amdgcn_mfma_f32_16x16x32_bf16(
                    ahi, bhi[fn], acc[fm][fn], 0, 0, 0);
                acc[fm][fn] = __builtin_amdgcn_mfma_f32_16x16x32_bf16(
                    ahi, blo[fn], acc[fm][fn], 0, 0, 0);
                acc[fm][fn] = __builtin_amdgcn_mfma_f32_16x16x32_bf16(
                    alo, bhi[fn], acc[fm][fn], 0, 0, 0);
            }
        }
    }

    // ---- epilogue: bias + store (scalar stores are 100% byte-efficient here)
    #pragma unroll
    for (int fm = 0; fm < 4; ++fm) {
        #pragma unroll
        for (int j = 0; j < 4; ++j) {
            const int o = o0 + wr * 64 + fm * 16 + lq * 4 + j;
            const float bv = bias[o];
            #pragma unroll
            for (int fn = 0; fn < 4; ++fn) {
                Y[((size_t)b * CC + o) * HWP + p0 + wc * 64 + fn * 16 + l16] =
                    acc[fm][fn][j] + bv;
            }
        }
    }
}

// Fused q/k/v projections: grid (2, 32, 48); z = which*16 + b
__global__ __launch_bounds__(256) void proj_qkv_kernel(
    const float* __restrict__ q, const float* __restrict__ Wq,
    const float* __restrict__ bq, float* __restrict__ qh,
    const float* __restrict__ k, const float* __restrict__ Wk,
    const float* __restrict__ bk, float* __restrict__ kh,
    const float* __restrict__ v, const float* __restrict__ Wv,
    const float* __restrict__ bv, float* __restrict__ vh)
{
    const int which = blockIdx.z >> 4;
    const int b     = blockIdx.z & 15;
    const float* X  = (which == 0) ? q  : (which == 1) ? k  : v;
    const float* W  = (which == 0) ? Wq : (which == 1) ? Wk : Wv;
    const float* bi = (which == 0) ? bq : (which == 1) ? bk : bv;
    float*       Y  = (which == 0) ? qh : (which == 1) ? kh : vh;
    proj_body(X, W, bi, Y, b, blockIdx.x * 128, blockIdx.y * 128);
}

// Output projection: grid (2, 32, 16)
__global__ __launch_bounds__(256) void proj_o_kernel(
    const float* __restrict__ X, const float* __restrict__ W,
    const float* __restrict__ bias, float* __restrict__ Y)
{
    proj_body(X, W, bias, Y, blockIdx.z, blockIdx.x * 128, blockIdx.y * 128);
}

// ---------------------------------------------------------------------------
// MFMA attention, block-per-slice: 4 waves, wave mt owns rows [mt*16, mt*16+16).
// LDS: Qs (Q rows, later P rows — row ranges are wave-private), Ks (K rows,
// later out rows — needs one barrier after QK^T), Vt (V transposed).
// Aliasing (attn_out~kh, out_pre~qh, slice-local, staged-first) -> NO
// __restrict__ on pointers.
// ---------------------------------------------------------------------------
__global__ __launch_bounds__(256) void attn_mfma_kernel(
    const float* qh, const float* kh, const float* vh,
    float* attn_out, float* out_pre)
{
    __shared__ float Qs[64][68];   // Q rows [h][w]; reused as P rows [h][g]
    __shared__ float Ks[64][68];   // K rows [g][w]; reused as out rows [h][w]
    __shared__ float Vt[64][68];   // V transposed [w][g]

    const int tid  = threadIdx.x;
    const int wid  = tid >> 6;
    const int lane = tid & 63;
    const int l16  = lane & 15;
    const int lq   = lane >> 4;

    const int s = blockIdx.x;
    const size_t base = (size_t)s * HWP;
    const float* Q = qh + base;
    const float* K = kh + base;
    const float* V = vh + base;

    // ---- stage Q, K natural (fully coalesced float4)
    #pragma unroll
    for (int i = 0; i < 4; ++i) {
        const int idx = tid + i * 256;
        const int row = idx >> 4, ch = (idx & 15) * 4;
        *(float4*)&Qs[row][ch] = *(const float4*)&Q[row * SW + ch];
        *(float4*)&Ks[row][ch] = *(const float4*)&K[row * SW + ch];
    }
    // ---- stage V transposed (4x4 register transpose)
    {
        const int tr = tid & 15, tc = tid >> 4;
        const float* src = V + (tc * 4) * SW + tr * 4;
        const float4 a0 = *(const float4*)(src);
        const float4 a1 = *(const float4*)(src + SW);
        const float4 a2 = *(const float4*)(src + 2 * SW);
        const float4 a3 = *(const float4*)(src + 3 * SW);
        *(float4*)&Vt[tr * 4 + 0][tc * 4] = make_float4(a0.x, a1.x, a2.x, a3.x);
        *(float4*)&Vt[tr * 4 + 1][tc * 4] = make_float4(a0.y, a1.y, a2.y, a3.y);
        *(float4*)&Vt[tr * 4 + 2][tc * 4] = make_float4(a0.z, a1.z, a2.z, a3.z);
        *(float4*)&Vt[tr * 4 + 3][tc * 4] = make_float4(a0.w, a1.w, a2.w, a3.w);
    }
    __syncthreads();

    const int mt = wid;    // wave's m-tile

    // ---- Q A-fragments for this wave's rows
    bf16x8 Qhi[2], Qlo[2];
    #pragma unroll
    for (int ks = 0; ks < 2; ++ks) {
        const float* srcq = &Qs[mt * 16 + l16][ks * 32 + lq * 8];
        split8(*(const float4*)srcq, *(const float4*)(srcq + 4), Qhi[ks], Qlo[ks]);
    }

    // ---- QK^T: acc[nt], C row = h = mt*16+lq*4+reg, col = g = nt*16+l16
    f32x4 acc[4] = {};
    #pragma unroll
    for (int nt = 0; nt < 4; ++nt) {
        #pragma unroll
        for (int ks = 0; ks < 2; ++ks) {
            const float* srck = &Ks[nt * 16 + l16][ks * 32 + lq * 8];
            bf16x8 Khi, Klo;
            split8(*(const float4*)srck, *(const float4*)(srck + 4), Khi, Klo);
            acc[nt] = __builtin_amdgcn_mfma_f32_16x16x32_bf16(
                Qhi[ks], Khi, acc[nt], 0, 0, 0);
            acc[nt] = __builtin_amdgcn_mfma_f32_16x16x32_bf16(
                Qhi[ks], Klo, acc[nt], 0, 0, 0);
            acc[nt] = __builtin_amdgcn_mfma_f32_16x16x32_bf16(
                Qlo[ks], Khi, acc[nt], 0, 0, 0);
        }
    }

    // ---- softmax per output row; write P into Qs (wave-private rows)
    #pragma unroll
    for (int r = 0; r < 4; ++r) {
        float l0 = acc[0][r] * 0.125f;
        float l1 = acc[1][r] * 0.125f;
        float l2 = acc[2][r] * 0.125f;
        float l3 = acc[3][r] * 0.125f;
        float m = fmaxf(fmaxf(l0, l1), fmaxf(l2, l3));
        m = fmaxf(m, __shfl_xor(m, 1));
        m = fmaxf(m, __shfl_xor(m, 2));
        m = fmaxf(m, __shfl_xor(m, 4));
        m = fmaxf(m, __shfl_xor(m, 8));
        const float e0 = __expf(l0 - m);
        const float e1 = __expf(l1 - m);
        const float e2 = __expf(l2 - m);
        const float e3 = __expf(l3 - m);
        float sum = e0 + e1 + e2 + e3;
        sum += __shfl_xor(sum, 1);
        sum += __shfl_xor(sum, 2);
        sum += __shfl_xor(sum, 4);
        sum += __shfl_xor(sum, 8);
        const float rs = 1.0f / sum;
        const int h = mt * 16 + lq * 4 + r;
        Qs[h][0 * 16 + l16] = e0 * rs;
        Qs[h][1 * 16 + l16] = e1 * rs;
        Qs[h][2 * 16 + l16] = e2 * rs;
        Qs[h][3 * 16 + l16] = e3 * rs;
    }

    // ---- attn store: coalesced float4 from Qs (wave-private rows)
    #pragma unroll
    for (int i = 0; i < 4; ++i) {
        const int idx = lane + i * 64;
        const int row = mt * 16 + (idx >> 4), ch = (idx & 15) * 4;
        *(float4*)&attn_out[base + (size_t)row * SH + ch] =
            *(const float4*)&Qs[row][ch];
    }

    __syncthreads();   // all waves done reading Ks (QK^T) -> can reuse for out

    // ---- PV: out[h][w] = sum_g P[h][g] V[g][w]
    f32x4 o[4] = {};
    #pragma unroll
    for (int ks = 0; ks < 2; ++ks) {
        const float* srcp = &Qs[mt * 16 + l16][ks * 32 + lq * 8];
        bf16x8 Phi, Plo;
        split8(*(const float4*)srcp, *(const float4*)(srcp + 4), Phi, Plo);
        #pragma unroll
        for (int nt = 0; nt < 4; ++nt) {
            const float* srcv = &Vt[nt * 16 + l16][ks * 32 + lq * 8];
            bf16x8 Vhi, Vlo;
            split8(*(const float4*)srcv, *(const float4*)(srcv + 4), Vhi, Vlo);
            o[nt] = __builtin_amdgcn_mfma_f32_16x16x32_bf16(
                Phi, Vhi, o[nt], 0, 0, 0);
            o[nt] = __builtin_amdgcn_mfma_f32_16x16x32_bf16(
                Phi, Vlo, o[nt], 0, 0, 0);
            o[nt] = __builtin_amdgcn_mfma_f32_16x16x32_bf16(
                Plo, Vhi, o[nt], 0, 0, 0);
        }
    }

    // ---- out store: bounce through Ks (wave-private rows), coalesced float4
    #pragma unroll
    for (int nt = 0; nt < 4; ++nt)
        #pragma unroll
        for (int r = 0; r < 4; ++r)
            Ks[mt * 16 + lq * 4 + r][nt * 16 + l16] = o[nt][r];
    #pragma unroll
    for (int i = 0; i < 4; ++i) {
        const int idx = lane + i * 64;
        const int row = mt * 16 + (idx >> 4), ch = (idx & 15) * 4;
        *(float4*)&out_pre[base + (size_t)row * SW + ch] =
            *(const float4*)&Ks[row][ch];
    }
}

// Memory plan (unchanged):
//   vh -> d_out[0:16.78M), kh -> d_out[16.78M:33.55M), qh -> ws, out_pre -> ws
extern "C" void kernel_launch(void* const* d_in, const int* in_sizes, int n_in,
                              void* d_out, int out_size, void* d_ws, size_t ws_size,
                              hipStream_t stream) {
    (void)in_sizes; (void)n_in; (void)out_size; (void)ws_size;

    const float* q  = (const float*)d_in[0];
    const float* k  = (const float*)d_in[1];
    const float* v  = (const float*)d_in[2];
    const float* Wq = (const float*)d_in[3];
    const float* bq = (const float*)d_in[4];
    const float* Wk = (const float*)d_in[5];
    const float* bk = (const float*)d_in[6];
    const float* Wv = (const float*)d_in[7];
    const float* bv = (const float*)d_in[8];
    const float* Wo = (const float*)d_in[9];
    const float* bo = (const float*)d_in[10];

    float* out  = (float*)d_out;
    float* attn = out + OUT_ELEMS;

    float* vh      = out;
    float* kh      = attn;
    float* qh      = (float*)d_ws;
    float* out_pre = qh;

    const dim3 blk(256);

    proj_qkv_kernel<<<dim3(2, 32, 48), blk, 0, stream>>>(
        q, Wq, bq, qh, k, Wk, bk, kh, v, Wv, bv, vh);

    attn_mfma_kernel<<<dim3(NSLICE), blk, 0, stream>>>(
        qh, kh, vh, attn, out_pre);

    proj_o_kernel<<<dim3(2, 32, 16), blk, 0, stream>>>(out_pre, Wo, bo, out);
}